// Round 6
// baseline (172.346 us; speedup 1.0000x reference)
//
#include <hip/hip_runtime.h>
#include <hip/hip_fp16.h>
#include <cstdint>
#include <cstddef>

#define T_DIM 5
#define F_DIM 8
#define Z_DIM 16
#define Y_DIM 96
#define X_DIM 96
#define NRAYS 32768
#define K_SAMP 128

// Pipeline (4 launches):
//   setup     : fused {transpose -> inp f16 [t][y][x][ci]} + {prep -> wB,bR} + {nearfar}
//   conv_mfma : fld f32 [t][zo][y][x] via v_mfma_f32_16x16x32_f16
//               256 thr / 4 waves (wave = y x xtile), LDS dbuf, reg-staged prefetch
//   pack      : fld -> cellp, cells stored as (lo, hi-lo) half2 pairs
//   render    : grid-space march, log2 optics, exec-masked cached reload pipelined
//               1 iter deep (same gather count, load->use = full optics chain)

struct __align__(16) Cell { __half2 h0, h1, h2, h3; };

typedef __attribute__((ext_vector_type(4))) float     f32x4;
typedef __attribute__((ext_vector_type(8))) _Float16  f16x8;

__device__ __forceinline__ float fexp2(float x) { return __builtin_amdgcn_exp2f(x); }   // v_exp_f32
__device__ __forceinline__ float flog2(float x) { return __builtin_amdgcn_logf(x); }    // v_log_f32

// blocks [0,480): transpose | [480,696): weight prep | [696,1336): nearfar
__global__ __launch_bounds__(256) void setup_kernel(
        const float* __restrict__ xin, __half* __restrict__ inp,
        const float* __restrict__ w, const float* __restrict__ cb,
        const float* __restrict__ dw, __half* __restrict__ wB, float* __restrict__ bR,
        const float* __restrict__ ro, const float* __restrict__ rd,
        float* __restrict__ nearA, float* __restrict__ farA) {
    int b = blockIdx.x;
    if (b < 480) {
        // ---- transpose: inp[((t*96+y)*96+x)*128 + f*16+z] = (half) vol[f][t][z][y][x]
        __shared__ __half lds[96 * 136];
        int t = b / 96, y = b - (b / 96) * 96;
        for (int i = threadIdx.x; i < 12288; i += 256) {
            int row = i / 96;
            int x   = i - row * 96;
            int f = row >> 4, z = row & 15;
            float v = xin[(((size_t)(f * 5 + t) * 16 + z) * 96 + y) * 96 + x];
            lds[x * 136 + row] = __float2half(v);
        }
        __syncthreads();
        __half* ob = inp + ((size_t)(t * 96 + y) * 96) * 128;
        for (int c = threadIdx.x; c < 1536; c += 256) {
            int x = c >> 4, sub = c & 15;
            uint4 v = *(const uint4*)(lds + x * 136 + sub * 8);
            *(uint4*)(ob + (size_t)x * 128 + sub * 8) = v;
        }
    } else if (b < 696) {
        // ---- weight prep: wB[((p*27+tap)*16+zo)*32+cs], ci = p*32+cs
        int i = (b - 480) * 256 + threadIdx.x;       // 0 .. 55295 exactly
        if (i < 16) {
            float s = 0.f;
            #pragma unroll
            for (int f = 0; f < 8; ++f) s += cb[f * 16 + i] * dw[f];
            bR[i] = s;
        }
        int cs  = i & 31;
        int zo  = (i >> 5) & 15;
        int pt  = i >> 9;
        int p   = pt / 27;
        int tap = pt - p * 27;
        int ci  = p * 32 + cs;
        float s = 0.f;
        #pragma unroll
        for (int f = 0; f < 8; ++f)
            s += w[(size_t)((f * 16 + zo) * 128 + ci) * 27 + tap] * dw[f];
        wB[i] = __float2half(s);
    } else {
        // ---- nearfar: per-ray near/far only
        int gid = (b - 696) * 256 + threadIdx.x;     // 0 .. 163839
        const float* o = ro + (size_t)gid * 3;
        const float* d = rd + (size_t)gid * 3;
        float ox = o[0], oy = o[1], oz = o[2];
        float dx = d[0], dy = d[1], dz = d[2];
        float t1x = (0.f - ox) / dx, t2x = (1.f - ox) / dx;
        float t1y = (0.f - oy) / dy, t2y = (1.f - oy) / dy;
        float t1z = (0.f - oz) / dz, t2z = (1.f - oz) / dz;
        float nr = fmaxf(fmaxf(fminf(t1x, t2x), fminf(t1y, t2y)), fminf(t1z, t2z));
        float fr = fminf(fminf(fmaxf(t1x, t2x), fmaxf(t1y, t2y)), fmaxf(t1z, t2z));
        nr = fmaxf(nr, 0.01f);
        fr = fmaxf(fr, nr + 1e-6f);
        nearA[gid] = nr;
        farA[gid]  = fr;
    }
}

// Block = (t, y-pair, 32-x seg), 256 thr = 4 waves: wid = (xt<<1)|w, wave computes
// y = y0+w, x-tile xt (16 x). Per wave per phase: 27 x {L1 weight, ds_read_b128, MFMA}.
// LDS: 2 buffers of [12 rows][34 x][4 slots of 8 halves], slot s' = sub ^ ((xl>>1)&3).
// Phase p: ds_write(buf[p&1]) -> barrier -> issue global loads(p+1) -> compute(buf[p&1]).
// Buffer safety: per-wave order C(p-1) < A(p) < B(p); one barrier per phase.
// 52 KB LDS -> 3 blocks/CU -> ~11 waves/CU (2x round-5's latency hiding, same traffic).
__global__ __launch_bounds__(256) void conv_mfma_kernel(
        const __half* __restrict__ inp, const __half* __restrict__ wB,
        const float* __restrict__ bR, float* __restrict__ fld) {
    int bid = blockIdx.x;
    int wg  = (bid & 7) * 90 + (bid >> 3);     // bijective XCD swizzle (720 = 8*90)
    int xs  = wg % 3;
    int rem = wg / 3;
    int yp  = rem % 48;
    int t   = rem / 48;
    int xseg = xs * 32, y0 = yp * 2;

    __shared__ __half lds[2][12 * 34 * 32];          // 2 x 26,112 B
    const int tid  = threadIdx.x;
    const int wid  = tid >> 6;
    const int w    = wid & 1;                        // output y = y0 + w
    const int xt   = wid >> 1;                       // x-tile 0/1
    const int lane = tid & 63;
    const int l15  = lane & 15;
    const int ksub = lane >> 4;

    // ---- main staging: 128 (xl,sub) columns x 12 rows; thread = (tid&127, rows rlo..rlo+5)
    const int l128 = tid & 127;
    const int xl0 = l128 >> 2, sub0 = l128 & 3;
    const int rlo = (tid >> 7) * 6;
    const int xg0 = xseg + xl0 - 1;
    const bool xok0 = (unsigned)xg0 < 96u;
    const int glo0 = xg0 * 128 + sub0 * 8;                       // halves (+p*32 later)
    const int lof0 = xl0 * 32 + ((sub0 ^ ((xl0 >> 1) & 3)) << 3);
    // ---- halo: 96 chunks (xl 32..33, sub 0..3, rows 0..11) -> threads 0..95, 1 each
    const int qh   = tid / 12;
    const int rowh = tid - qh * 12;
    const int xl1  = 32 + (qh >> 2), sub1 = qh & 3;
    const bool hwr = (tid < 96);
    const int xg1  = xseg + xl1 - 1;
    const bool hld = hwr && ((unsigned)xg1 < 96u);
    const int glo1 = xg1 * 128 + sub1 * 8;
    const int lof1 = xl1 * 32 + ((sub1 ^ ((xl1 >> 1) & 3)) << 3);

    // ---- swizzled B-fragment read offsets for this wave's tile (halves) ----
    int offA[3];
    #pragma unroll
    for (int kx = 0; kx < 3; ++kx) {
        int X = xt * 16 + l15 + kx;
        offA[kx] = X * 32 + ((ksub ^ ((X >> 1) & 3)) << 3);
    }

    uint4 vm[6];
    uint4 vh;
    f32x4 acc = {0.f, 0.f, 0.f, 0.f};

    // ---- prologue: issue loads for p=0 ----
    #pragma unroll
    for (int rr = 0; rr < 6; ++rr) {
        int r = rlo + rr;
        int tt = t + (r >> 2) - 1;
        int yy = y0 + (r & 3) - 1;
        bool rok = ((unsigned)tt < 5u) & ((unsigned)yy < 96u);
        int rbase = (tt * 96 + yy) * 12288;
        uint4 v = {0u, 0u, 0u, 0u};
        if (rok & xok0) v = *(const uint4*)(inp + rbase + glo0);
        vm[rr] = v;
    }
    {
        int tt = t + (rowh >> 2) - 1;
        int yy = y0 + (rowh & 3) - 1;
        bool rok = ((unsigned)tt < 5u) & ((unsigned)yy < 96u);
        int rbase = (tt * 96 + yy) * 12288;
        uint4 v = {0u, 0u, 0u, 0u};
        if (rok & hld) v = *(const uint4*)(inp + rbase + glo1);
        vh = v;
    }

    #pragma unroll
    for (int p = 0; p < 4; ++p) {
        __half* L = &lds[p & 1][0];
        // ---- A(p): commit staged regs to LDS ----
        #pragma unroll
        for (int rr = 0; rr < 6; ++rr)
            *(uint4*)(L + (rlo + rr) * 1088 + lof0) = vm[rr];
        if (hwr)
            *(uint4*)(L + rowh * 1088 + lof1) = vh;
        __syncthreads();                               // B(p)

        // ---- issue loads for p+1 (hidden under compute below) ----
        if (p < 3) {
            #pragma unroll
            for (int rr = 0; rr < 6; ++rr) {
                int r = rlo + rr;
                int tt = t + (r >> 2) - 1;
                int yy = y0 + (r & 3) - 1;
                bool rok = ((unsigned)tt < 5u) & ((unsigned)yy < 96u);
                int rbase = (tt * 96 + yy) * 12288 + ((p + 1) << 5);
                uint4 v = {0u, 0u, 0u, 0u};
                if (rok & xok0) v = *(const uint4*)(inp + rbase + glo0);
                vm[rr] = v;
            }
            {
                int tt = t + (rowh >> 2) - 1;
                int yy = y0 + (rowh & 3) - 1;
                bool rok = ((unsigned)tt < 5u) & ((unsigned)yy < 96u);
                int rbase = (tt * 96 + yy) * 12288 + ((p + 1) << 5);
                uint4 v = {0u, 0u, 0u, 0u};
                if (rok & hld) v = *(const uint4*)(inp + rbase + glo1);
                vh = v;
            }
        }

        // ---- C(p): 27 taps x (1 L1 weight load + 1 ds_read_b128 + 1 MFMA) ----
        const __half* wp_base = wB + (size_t)p * 13824 + l15 * 32 + ksub * 8;
        #pragma unroll
        for (int kt = 0; kt < 3; ++kt) {
            #pragma unroll
            for (int ky = 0; ky < 3; ++ky) {
                const __half* lrow = L + (kt * 4 + w + ky) * 1088;
                #pragma unroll
                for (int kx = 0; kx < 3; ++kx) {
                    int tap = (kt * 3 + ky) * 3 + kx;
                    f16x8 aw = *(const f16x8*)(wp_base + tap * 512);
                    f16x8 bb = *(const f16x8*)(lrow + offA[kx]);
                    acc = __builtin_amdgcn_mfma_f32_16x16x32_f16(aw, bb, acc, 0, 0, 0);
                }
            }
        }
    }

    // ---- epilogue: D[row=zo=(ksub*4+r)][col=x=l15]; 64B lane-contiguous stores ----
    int yw = y0 + w;
    #pragma unroll
    for (int r = 0; r < 4; ++r) {
        int zo = ksub * 4 + r;
        float bz = bR[zo];
        size_t o = (((size_t)t * 16 + zo) * 96 + yw) * 96 + xseg + xt * 16 + l15;
        fld[o] = acc[r] + bz;
    }
}

// cellp[t][z][y][x]: 4 half2 of (lo, hi-lo) along x for the 4 (z,y) corner rows.
__global__ __launch_bounds__(256) void pack_kernel(
        const float* __restrict__ fld, Cell* __restrict__ cellp) {
    int i = blockIdx.x * 256 + threadIdx.x;
    if (i >= 737280) return;
    int x = i % 96;
    int r = i / 96;
    int y = r % 96;
    int r2 = r / 96;
    int z = r2 % 16;
    int t = r2 / 16;
    const float* ft = fld + (size_t)t * 147456;
    int xp = min(x + 1, 95);
    int yr0 = y * 96, yr1 = min(y + 1, 95) * 96;
    int zr0 = z * 9216, zr1 = min(z + 1, 15) * 9216;
    float c000 = ft[zr0 + yr0 + x], c001 = ft[zr0 + yr0 + xp];
    float c010 = ft[zr0 + yr1 + x], c011 = ft[zr0 + yr1 + xp];
    float c100 = ft[zr1 + yr0 + x], c101 = ft[zr1 + yr0 + xp];
    float c110 = ft[zr1 + yr1 + x], c111 = ft[zr1 + yr1 + xp];
    Cell cl;
    cl.h0 = __floats2half2_rn(c000, c001 - c000);
    cl.h1 = __floats2half2_rn(c010, c011 - c010);
    cl.h2 = __floats2half2_rn(c100, c101 - c100);
    cl.h3 = __floats2half2_rn(c110, c111 - c110);
    cellp[i] = cl;
}

// 4 lanes per ray, 32 samples each. Grid-space march; log2-domain optics.
// Masked cached reload, pipelined 1 iteration: sample k+1's index + masked gather
// issue BEFORE sample k's optics -> load-to-use = full optics chain, gather count
// unchanged vs round 5 (the proven-minimal memory shape).
__global__ __launch_bounds__(256) void render_kernel(
        const float* __restrict__ ro, const float* __restrict__ rd,
        const Cell* __restrict__ cellp,
        const float* __restrict__ nearA, const float* __restrict__ farA,
        const float* __restrict__ dens_b, float* __restrict__ out) {
    int b = blockIdx.x;                 // 0..2559
    int b7 = b & 7, bhi = b >> 3;
    int t, seg;
    if (b7 < 5) { t = b7; seg = bhi; }
    else { int j = (b7 - 5) * 320 + bhi; t = j / 192; seg = 320 + j % 192; }
    int c = threadIdx.x & 3;
    int ray = t * NRAYS + seg * 64 + (threadIdx.x >> 2);

    const float* o = ro + (size_t)ray * 3;
    const float* d = rd + (size_t)ray * 3;
    float ox = o[0], oy = o[1], oz = o[2];
    float dx = d[0], dy = d[1], dz = d[2];
    float nr = nearA[ray], fr = farA[ray];
    const Cell* vt = cellp + (size_t)t * 147456;
    const float L2E = 1.4426950408889634f;
    float db2 = dens_b[0] * L2E;

    float span = fr - nr;
    float step = span * 0.0078125f;
    float s  = fmaf((float)(c * 32), step, nr);
    float mid = s + 0.5f * step;
    float pxg = fmaf(dx, mid, ox) * 95.f;
    float pyg = fmaf(dy, mid, oy) * 95.f;
    float pzg = fmaf(dz, mid, oz) * 15.f;
    float ddxg = dx * step * 95.f, ddyg = dy * step * 95.f, ddzg = dz * step * 15.f;

    // prime: sample 0 (consumed samples are in-box -> int clamps suffice; fracs
    // identical to float-clamp path for all consumed samples)
    int x0 = min(max((int)pxg, 0), 94);
    int y0 = min(max((int)pyg, 0), 94);
    int z0 = min(max((int)pzg, 0), 14);
    float cfx = pxg - (float)x0, cfy = pyg - (float)y0, cfz = pzg - (float)z0;
    int pidx = z0 * 9216 + y0 * 96 + x0;
    Cell cl = vt[pidx];

    float num = 0.f, den = 0.f, A2 = 0.f;
    float trans = 1.f;
    for (int kk = 0; kk < 32; ++kk) {
        // advance to sample k+1, issue masked prefetch (k=31's result is discarded)
        pxg += ddxg; pyg += ddyg; pzg += ddzg;
        int nx = min(max((int)pxg, 0), 94);
        int ny = min(max((int)pyg, 0), 94);
        int nz = min(max((int)pzg, 0), 14);
        float nfx = pxg - (float)nx, nfy = pyg - (float)ny, nfz = pzg - (float)nz;
        int nidx = nz * 9216 + ny * 96 + nx;
        Cell cn = cl;
        if (nidx != pidx) {                // exec-masked 16B gather, changed lanes only
            pidx = nidx;
            cn = vt[nidx];
        }

        // optics on sample k ((lo, hi-lo) packed cells -> v_fma_mix lerps)
        float v00 = fmaf(cfx, __half2float(__high2half(cl.h0)), __half2float(__low2half(cl.h0)));
        float v01 = fmaf(cfx, __half2float(__high2half(cl.h1)), __half2float(__low2half(cl.h1)));
        float v10 = fmaf(cfx, __half2float(__high2half(cl.h2)), __half2float(__low2half(cl.h2)));
        float v11 = fmaf(cfx, __half2float(__high2half(cl.h3)), __half2float(__low2half(cl.h3)));
        float v0  = fmaf(cfy, v01 - v00, v00);
        float v1  = fmaf(cfy, v11 - v10, v10);
        float pre2 = fmaf(fmaf(cfz, v1 - v0, v0), L2E, db2);     // (pre+db)*log2e

        float u = fexp2(-fabsf(pre2));
        float dens2 = fmaxf(pre2, 0.f) + flog2(1.f + u);         // softplus * log2e
        float dd2 = dens2 * step;                                 // dd * log2e
        float ex = fexp2(-dd2);                                   // exp(-dd)
        float wgt = (1.f - ex) * trans;
        num = fmaf(wgt, s, num);
        den += wgt;
        trans *= ex;
        A2 += dd2;
        s += step;

        cl = cn; cfx = nfx; cfy = nfy; cfz = nfz;
    }
    int lane = threadIdx.x & 63;
    int qb = lane & ~3;
    float A0 = __shfl(A2, qb,     64);
    float A1 = __shfl(A2, qb + 1, 64);
    float Ab = __shfl(A2, qb + 2, 64);
    float P = 0.f;
    if (c > 0) P += A0;
    if (c > 1) P += A1;
    if (c > 2) P += Ab;
    float sc = fexp2(-P);
    float numc = num * sc;
    float denc = den * sc;
    numc += __shfl_xor(numc, 1, 64);
    numc += __shfl_xor(numc, 2, 64);
    denc += __shfl_xor(denc, 1, 64);
    denc += __shfl_xor(denc, 2, 64);
    if (c == 0) {
        float depth = numc / (denc + 1e-10f);
        // per-ray clamp [near, s_last]; equals ref's global clamp to ~1e-8
        float slast = fmaf(0.9921875f, span, nr);
        depth = fminf(fmaxf(depth, nr), slast);
        out[ray] = depth;
    }
}

extern "C" void kernel_launch(void* const* d_in, const int* in_sizes, int n_in,
                              void* d_out, int out_size, void* d_ws, size_t ws_size,
                              hipStream_t stream) {
    const float* vol = (const float*)d_in[0];
    const float* ro  = (const float*)d_in[1];
    const float* rd  = (const float*)d_in[2];
    const float* cw  = (const float*)d_in[3];
    const float* cb  = (const float*)d_in[4];
    const float* dw  = (const float*)d_in[5];
    const float* dbp = (const float*)d_in[6];
    float* out = (float*)d_out;

    float* ws      = (float*)d_ws;
    float* fld     = ws;                                    // [0 .. 737,280)
    __half* inp    = (__half*)(ws + 737280);                // 5,898,240 halves
    Cell*  cellp   = (Cell*)(ws + 737280);                  // overlaps dead inp
    __half* wB     = (__half*)(ws + 737280 + 2949120);      // 55,296 halves
    float* bR      = ws + 737280 + 2949120 + 27648;         // 16 (+pad to 32)
    float* nearA   = bR + 32;
    float* farA    = nearA + 163840;

    hipLaunchKernelGGL(setup_kernel, dim3(1336), dim3(256), 0, stream,
                       vol, inp, cw, cb, dw, wB, bR, ro, rd, nearA, farA);
    hipLaunchKernelGGL(conv_mfma_kernel, dim3(720), dim3(256), 0, stream,
                       inp, wB, bR, fld);
    hipLaunchKernelGGL(pack_kernel, dim3(2880), dim3(256), 0, stream, fld, cellp);
    hipLaunchKernelGGL(render_kernel, dim3(2560), dim3(256), 0, stream,
                       ro, rd, cellp, nearA, farA, dbp, out);
}

// Round 7
// 161.374 us; speedup vs baseline: 1.0680x; 1.0680x over previous
//
#include <hip/hip_runtime.h>
#include <hip/hip_fp16.h>
#include <cstdint>
#include <cstddef>

#define T_DIM 5
#define F_DIM 8
#define Z_DIM 16
#define Y_DIM 96
#define X_DIM 96
#define NRAYS 32768
#define K_SAMP 128

// Pipeline (4 launches):
//   setup     : fused {transpose -> inp f16 [t][y][x][ci]} + {prep -> wB,bR} + {nearfar}
//   conv_mfma : fld f32 [t][zo][y][x] via v_mfma_f32_16x16x32_f16  (round-5 proven config:
//               128 thr / 2 waves, dual acc chains, 2 MFMA per weight load, LDS dbuf)
//   pack      : fld -> cellp, cells stored as (lo, hi-lo) half2 pairs
//   render    : 8 lanes/ray x 16 samples (2x schedulable waves), grid-space march,
//               log2 optics, exec-masked cached reload (round-5 memory shape)

struct __align__(16) Cell { __half2 h0, h1, h2, h3; };

typedef __attribute__((ext_vector_type(4))) float     f32x4;
typedef __attribute__((ext_vector_type(8))) _Float16  f16x8;

__device__ __forceinline__ float fexp2(float x) { return __builtin_amdgcn_exp2f(x); }   // v_exp_f32
__device__ __forceinline__ float flog2(float x) { return __builtin_amdgcn_logf(x); }    // v_log_f32

// blocks [0,480): transpose | [480,696): weight prep | [696,1336): nearfar
__global__ __launch_bounds__(256) void setup_kernel(
        const float* __restrict__ xin, __half* __restrict__ inp,
        const float* __restrict__ w, const float* __restrict__ cb,
        const float* __restrict__ dw, __half* __restrict__ wB, float* __restrict__ bR,
        const float* __restrict__ ro, const float* __restrict__ rd,
        float* __restrict__ nearA, float* __restrict__ farA) {
    int b = blockIdx.x;
    if (b < 480) {
        // ---- transpose: inp[((t*96+y)*96+x)*128 + f*16+z] = (half) vol[f][t][z][y][x]
        __shared__ __half lds[96 * 136];
        int t = b / 96, y = b - (b / 96) * 96;
        for (int i = threadIdx.x; i < 12288; i += 256) {
            int row = i / 96;
            int x   = i - row * 96;
            int f = row >> 4, z = row & 15;
            float v = xin[(((size_t)(f * 5 + t) * 16 + z) * 96 + y) * 96 + x];
            lds[x * 136 + row] = __float2half(v);
        }
        __syncthreads();
        __half* ob = inp + ((size_t)(t * 96 + y) * 96) * 128;
        for (int c = threadIdx.x; c < 1536; c += 256) {
            int x = c >> 4, sub = c & 15;
            uint4 v = *(const uint4*)(lds + x * 136 + sub * 8);
            *(uint4*)(ob + (size_t)x * 128 + sub * 8) = v;
        }
    } else if (b < 696) {
        // ---- weight prep: wB[((p*27+tap)*16+zo)*32+cs], ci = p*32+cs
        int i = (b - 480) * 256 + threadIdx.x;       // 0 .. 55295 exactly
        if (i < 16) {
            float s = 0.f;
            #pragma unroll
            for (int f = 0; f < 8; ++f) s += cb[f * 16 + i] * dw[f];
            bR[i] = s;
        }
        int cs  = i & 31;
        int zo  = (i >> 5) & 15;
        int pt  = i >> 9;
        int p   = pt / 27;
        int tap = pt - p * 27;
        int ci  = p * 32 + cs;
        float s = 0.f;
        #pragma unroll
        for (int f = 0; f < 8; ++f)
            s += w[(size_t)((f * 16 + zo) * 128 + ci) * 27 + tap] * dw[f];
        wB[i] = __float2half(s);
    } else {
        // ---- nearfar: per-ray near/far only
        int gid = (b - 696) * 256 + threadIdx.x;     // 0 .. 163839
        const float* o = ro + (size_t)gid * 3;
        const float* d = rd + (size_t)gid * 3;
        float ox = o[0], oy = o[1], oz = o[2];
        float dx = d[0], dy = d[1], dz = d[2];
        float t1x = (0.f - ox) / dx, t2x = (1.f - ox) / dx;
        float t1y = (0.f - oy) / dy, t2y = (1.f - oy) / dy;
        float t1z = (0.f - oz) / dz, t2z = (1.f - oz) / dz;
        float nr = fmaxf(fmaxf(fminf(t1x, t2x), fminf(t1y, t2y)), fminf(t1z, t2z));
        float fr = fminf(fminf(fmaxf(t1x, t2x), fmaxf(t1y, t2y)), fmaxf(t1z, t2z));
        nr = fmaxf(nr, 0.01f);
        fr = fmaxf(fr, nr + 1e-6f);
        nearA[gid] = nr;
        farA[gid]  = fr;
    }
}

// Block = (t, y-pair, 32-x seg), 128 thr (2 waves; wave w -> y = y0+w, two 16-x tiles).
// LDS: 2 buffers of [12 rows][34 x][4 slots of 8 halves], slot s' = sub ^ ((xl>>1)&3).
// Phase p: ds_write(buf[p&1]) -> barrier -> issue global loads(p+1) -> compute(buf[p&1]).
// Buffer safety: per-wave order C(p-1) < A(p) < B(p); one barrier per phase.
// Each 1KB weight load feeds TWO MFMAs (acc0/acc1) -> halves weight L1 traffic and
// gives 2 independent accumulation chains (round-6's 1:1 mapping regressed on both).
__global__ __launch_bounds__(128) void conv_mfma_kernel(
        const __half* __restrict__ inp, const __half* __restrict__ wB,
        const float* __restrict__ bR, float* __restrict__ fld) {
    int bid = blockIdx.x;
    int wg  = (bid & 7) * 90 + (bid >> 3);     // bijective XCD swizzle (720 = 8*90)
    int xs  = wg % 3;
    int rem = wg / 3;
    int yp  = rem % 48;
    int t   = rem / 48;
    int xseg = xs * 32, y0 = yp * 2;

    __shared__ __half lds[2][12 * 34 * 32];          // 2 x 26,112 B
    const int w    = threadIdx.x >> 6;
    const int lane = threadIdx.x & 63;
    const int l15  = lane & 15;
    const int ksub = lane >> 4;

    // ---- main staging columns: 128 lanes x 12 rows (xl 0..31, sub 0..3) ----
    const int xl0 = threadIdx.x >> 2, sub0 = threadIdx.x & 3;
    const int xg0 = xseg + xl0 - 1;
    const bool xok0 = (unsigned)xg0 < 96u;
    const int glo0 = xg0 * 128 + sub0 * 8;                       // halves (+p*32 later)
    const int lof0 = xl0 * 32 + ((sub0 ^ ((xl0 >> 1) & 3)) << 3);
    // ---- halo: 96 chunks (xl 32..33, sub 0..3, rows 0..11) -> lanes 0..95, 1 each ----
    const int q    = threadIdx.x / 12;                           // 0..10
    const int rowh = threadIdx.x - q * 12;                       // 0..11
    const int xl1  = 32 + (q >> 2), sub1 = q & 3;
    const int xg1  = xseg + xl1 - 1;
    const bool hwr = (q < 8);
    const bool hld = hwr && ((unsigned)xg1 < 96u);
    const int glo1 = xg1 * 128 + sub1 * 8;
    const int lof1 = xl1 * 32 + ((sub1 ^ ((xl1 >> 1) & 3)) << 3);

    // ---- swizzled B-fragment read offsets (halves) ----
    int offA[3];
    #pragma unroll
    for (int kx = 0; kx < 3; ++kx) {
        int X = l15 + kx;
        offA[kx] = X * 32 + ((ksub ^ ((X >> 1) & 3)) << 3);      // tile B = +512
    }

    uint4 vm[12];
    uint4 vh;
    f32x4 acc0 = {0.f, 0.f, 0.f, 0.f};
    f32x4 acc1 = {0.f, 0.f, 0.f, 0.f};

    // ---- prologue: issue loads for p=0 ----
    #pragma unroll
    for (int r = 0; r < 12; ++r) {
        int tt = t + (r >> 2) - 1;
        int yy = y0 + (r & 3) - 1;
        bool rok = ((unsigned)tt < 5u) & ((unsigned)yy < 96u);
        int rbase = (tt * 96 + yy) * 12288;
        uint4 v = {0u, 0u, 0u, 0u};
        if (rok & xok0) v = *(const uint4*)(inp + rbase + glo0);
        vm[r] = v;
    }
    {
        int tt = t + (rowh >> 2) - 1;
        int yy = y0 + (rowh & 3) - 1;
        bool rok = ((unsigned)tt < 5u) & ((unsigned)yy < 96u);
        int rbase = (tt * 96 + yy) * 12288;
        uint4 v = {0u, 0u, 0u, 0u};
        if (rok & hld) v = *(const uint4*)(inp + rbase + glo1);
        vh = v;
    }

    #pragma unroll
    for (int p = 0; p < 4; ++p) {
        __half* L = &lds[p & 1][0];
        // ---- A(p): commit staged regs to LDS ----
        #pragma unroll
        for (int r = 0; r < 12; ++r)
            *(uint4*)(L + r * 1088 + lof0) = vm[r];
        if (hwr)
            *(uint4*)(L + rowh * 1088 + lof1) = vh;
        __syncthreads();                               // B(p)

        // ---- issue loads for p+1 (hidden under compute below) ----
        if (p < 3) {
            #pragma unroll
            for (int r = 0; r < 12; ++r) {
                int tt = t + (r >> 2) - 1;
                int yy = y0 + (r & 3) - 1;
                bool rok = ((unsigned)tt < 5u) & ((unsigned)yy < 96u);
                int rbase = (tt * 96 + yy) * 12288 + ((p + 1) << 5);
                uint4 v = {0u, 0u, 0u, 0u};
                if (rok & xok0) v = *(const uint4*)(inp + rbase + glo0);
                vm[r] = v;
            }
            {
                int tt = t + (rowh >> 2) - 1;
                int yy = y0 + (rowh & 3) - 1;
                bool rok = ((unsigned)tt < 5u) & ((unsigned)yy < 96u);
                int rbase = (tt * 96 + yy) * 12288 + ((p + 1) << 5);
                uint4 v = {0u, 0u, 0u, 0u};
                if (rok & hld) v = *(const uint4*)(inp + rbase + glo1);
                vh = v;
            }
        }

        // ---- C(p): 27 taps x (1 L1 weight load + 2 ds_read_b128 + 2 MFMA) ----
        const __half* wp_base = wB + (size_t)p * 13824 + l15 * 32 + ksub * 8;
        #pragma unroll
        for (int kt = 0; kt < 3; ++kt) {
            #pragma unroll
            for (int ky = 0; ky < 3; ++ky) {
                const __half* lrow = L + (kt * 4 + w + ky) * 1088;
                #pragma unroll
                for (int kx = 0; kx < 3; ++kx) {
                    int tap = (kt * 3 + ky) * 3 + kx;
                    f16x8 aw = *(const f16x8*)(wp_base + tap * 512);
                    f16x8 b0 = *(const f16x8*)(lrow + offA[kx]);
                    acc0 = __builtin_amdgcn_mfma_f32_16x16x32_f16(aw, b0, acc0, 0, 0, 0);
                    f16x8 b1 = *(const f16x8*)(lrow + offA[kx] + 512);
                    acc1 = __builtin_amdgcn_mfma_f32_16x16x32_f16(aw, b1, acc1, 0, 0, 0);
                }
            }
        }
    }

    // ---- epilogue: D[row=zo=(ksub*4+r)][col=x=l15]; lane-contiguous 64B stores ----
    int yw = y0 + w;
    #pragma unroll
    for (int r = 0; r < 4; ++r) {
        int zo = ksub * 4 + r;
        float bz = bR[zo];
        size_t o = (((size_t)t * 16 + zo) * 96 + yw) * 96 + xseg + l15;
        fld[o]      = acc0[r] + bz;
        fld[o + 16] = acc1[r] + bz;
    }
}

// cellp[t][z][y][x]: 4 half2 of (lo, hi-lo) along x for the 4 (z,y) corner rows.
__global__ __launch_bounds__(256) void pack_kernel(
        const float* __restrict__ fld, Cell* __restrict__ cellp) {
    int i = blockIdx.x * 256 + threadIdx.x;
    if (i >= 737280) return;
    int x = i % 96;
    int r = i / 96;
    int y = r % 96;
    int r2 = r / 96;
    int z = r2 % 16;
    int t = r2 / 16;
    const float* ft = fld + (size_t)t * 147456;
    int xp = min(x + 1, 95);
    int yr0 = y * 96, yr1 = min(y + 1, 95) * 96;
    int zr0 = z * 9216, zr1 = min(z + 1, 15) * 9216;
    float c000 = ft[zr0 + yr0 + x], c001 = ft[zr0 + yr0 + xp];
    float c010 = ft[zr0 + yr1 + x], c011 = ft[zr0 + yr1 + xp];
    float c100 = ft[zr1 + yr0 + x], c101 = ft[zr1 + yr0 + xp];
    float c110 = ft[zr1 + yr1 + x], c111 = ft[zr1 + yr1 + xp];
    Cell cl;
    cl.h0 = __floats2half2_rn(c000, c001 - c000);
    cl.h1 = __floats2half2_rn(c010, c011 - c010);
    cl.h2 = __floats2half2_rn(c100, c101 - c100);
    cl.h3 = __floats2half2_rn(c110, c111 - c110);
    cellp[i] = cl;
}

// 8 lanes per ray, 16 samples each (2x schedulable waves vs 4-lane split).
// Grid-space march; log2-domain optics; exec-masked cached cell reload.
__global__ __launch_bounds__(256) void render_kernel(
        const float* __restrict__ ro, const float* __restrict__ rd,
        const Cell* __restrict__ cellp,
        const float* __restrict__ nearA, const float* __restrict__ farA,
        const float* __restrict__ dens_b, float* __restrict__ out) {
    int b = blockIdx.x;                 // 0..5119
    int b7 = b & 7, bhi = b >> 3;       // bhi 0..639
    int t, seg;
    if (b7 < 5) { t = b7; seg = bhi; }                       // XCD 0..4: one t each
    else { int j = (b7 - 5) * 640 + bhi; t = j / 384; seg = 640 + j % 384; }
    int c = threadIdx.x & 7;
    int ray = t * NRAYS + seg * 32 + (threadIdx.x >> 3);

    const float* o = ro + (size_t)ray * 3;
    const float* d = rd + (size_t)ray * 3;
    float ox = o[0], oy = o[1], oz = o[2];
    float dx = d[0], dy = d[1], dz = d[2];
    float nr = nearA[ray], fr = farA[ray];
    const Cell* vt = cellp + (size_t)t * 147456;
    const float L2E = 1.4426950408889634f;
    float db2 = dens_b[0] * L2E;

    float span = fr - nr;
    float step = span * 0.0078125f;
    float s  = fmaf((float)(c * 16), step, nr);
    float mid = s + 0.5f * step;
    float pxg = fmaf(dx, mid, ox) * 95.f;
    float pyg = fmaf(dy, mid, oy) * 95.f;
    float pzg = fmaf(dz, mid, oz) * 15.f;
    float ddxg = dx * step * 95.f, ddyg = dy * step * 95.f, ddzg = dz * step * 15.f;

    float num = 0.f, den = 0.f, A2 = 0.f;
    float trans = 1.f;
    int pidx = -1;
    Cell cl;
    for (int kk = 0; kk < 16; ++kk) {
        // consumed samples are in-box -> int clamps suffice (fracs identical)
        int x0 = min(max((int)pxg, 0), 94);
        int y0 = min(max((int)pyg, 0), 94);
        int z0 = min(max((int)pzg, 0), 14);
        float fx = pxg - (float)x0, fy = pyg - (float)y0, fz = pzg - (float)z0;

        int idx = z0 * 9216 + y0 * 96 + x0;
        if (idx != pidx) {                 // exec-masked 16B gather, changed lanes only
            pidx = idx;
            cl = vt[idx];
        }

        // (lo, hi-lo) packed cells -> v_fma_mix lerps
        float v00 = fmaf(fx, __half2float(__high2half(cl.h0)), __half2float(__low2half(cl.h0)));
        float v01 = fmaf(fx, __half2float(__high2half(cl.h1)), __half2float(__low2half(cl.h1)));
        float v10 = fmaf(fx, __half2float(__high2half(cl.h2)), __half2float(__low2half(cl.h2)));
        float v11 = fmaf(fx, __half2float(__high2half(cl.h3)), __half2float(__low2half(cl.h3)));
        float v0  = fmaf(fy, v01 - v00, v00);
        float v1  = fmaf(fy, v11 - v10, v10);
        float pre2 = fmaf(fmaf(fz, v1 - v0, v0), L2E, db2);      // (pre+db)*log2e

        float u = fexp2(-fabsf(pre2));
        float dens2 = fmaxf(pre2, 0.f) + flog2(1.f + u);         // softplus * log2e
        float dd2 = dens2 * step;                                 // dd * log2e
        float ex = fexp2(-dd2);                                   // exp(-dd)
        float wgt = (1.f - ex) * trans;
        num = fmaf(wgt, s, num);
        den += wgt;
        trans *= ex;
        A2 += dd2;
        s += step; pxg += ddxg; pyg += ddyg; pzg += ddzg;
    }
    // prefix transmittance across the 8 chunks of this ray
    int lane = threadIdx.x & 63;
    int qb = lane & ~7;
    float P = 0.f;
    #pragma unroll
    for (int j = 0; j < 7; ++j) {
        float Aj = __shfl(A2, qb + j, 64);
        P += (c > j) ? Aj : 0.f;
    }
    float sc = fexp2(-P);
    float numc = num * sc;
    float denc = den * sc;
    numc += __shfl_xor(numc, 1, 64);
    numc += __shfl_xor(numc, 2, 64);
    numc += __shfl_xor(numc, 4, 64);
    denc += __shfl_xor(denc, 1, 64);
    denc += __shfl_xor(denc, 2, 64);
    denc += __shfl_xor(denc, 4, 64);
    if (c == 0) {
        float depth = numc / (denc + 1e-10f);
        // per-ray clamp [near, s_last]; equals ref's global clamp to ~1e-8
        float slast = fmaf(0.9921875f, span, nr);
        depth = fminf(fmaxf(depth, nr), slast);
        out[ray] = depth;
    }
}

extern "C" void kernel_launch(void* const* d_in, const int* in_sizes, int n_in,
                              void* d_out, int out_size, void* d_ws, size_t ws_size,
                              hipStream_t stream) {
    const float* vol = (const float*)d_in[0];
    const float* ro  = (const float*)d_in[1];
    const float* rd  = (const float*)d_in[2];
    const float* cw  = (const float*)d_in[3];
    const float* cb  = (const float*)d_in[4];
    const float* dw  = (const float*)d_in[5];
    const float* dbp = (const float*)d_in[6];
    float* out = (float*)d_out;

    float* ws      = (float*)d_ws;
    float* fld     = ws;                                    // [0 .. 737,280)
    __half* inp    = (__half*)(ws + 737280);                // 5,898,240 halves
    Cell*  cellp   = (Cell*)(ws + 737280);                  // overlaps dead inp
    __half* wB     = (__half*)(ws + 737280 + 2949120);      // 55,296 halves
    float* bR      = ws + 737280 + 2949120 + 27648;         // 16 (+pad to 32)
    float* nearA   = bR + 32;
    float* farA    = nearA + 163840;

    hipLaunchKernelGGL(setup_kernel, dim3(1336), dim3(256), 0, stream,
                       vol, inp, cw, cb, dw, wB, bR, ro, rd, nearA, farA);
    hipLaunchKernelGGL(conv_mfma_kernel, dim3(720), dim3(128), 0, stream,
                       inp, wB, bR, fld);
    hipLaunchKernelGGL(pack_kernel, dim3(2880), dim3(256), 0, stream, fld, cellp);
    hipLaunchKernelGGL(render_kernel, dim3(5120), dim3(256), 0, stream,
                       ro, rd, cellp, nearA, farA, dbp, out);
}